// Round 4
// baseline (547.151 us; speedup 1.0000x reference)
//
#include <hip/hip_runtime.h>

#define B_N 4096
#define T_N 64
#define K_N 512
#define D_N 64

// ws layout:
//   [0, 131072)        : c2[t*K+k]  (32768 floats)
//   [131072, 262144)   : used[t*K+k] (32768 uints)
//   [262144, 262152)   : loss_sum (double)   (zeroed together with used via memset)

// |c|^2 per code: pre-rounded squares, sequential ascending-d adds (matches jnp).
__global__ __launch_bounds__(256) void c2_kernel(const float* __restrict__ cb,
                                                 float* __restrict__ c2) {
    int i = blockIdx.x * 256 + threadIdx.x;   // < 32768
    const float4* c = reinterpret_cast<const float4*>(cb + (size_t)i * D_N);
    float s = 0.0f;
#pragma unroll
    for (int j = 0; j < 16; ++j) {
        float4 v = c[j];
        s = __fadd_rn(s, __fmul_rn(v.x, v.x));
        s = __fadd_rn(s, __fmul_rn(v.y, v.y));
        s = __fadd_rn(s, __fmul_rn(v.z, v.z));
        s = __fadd_rn(s, __fmul_rn(v.w, v.w));
    }
    c2[i] = s;
}

// Main: one thread per (b,t) row, z pinned in VGPRs (launch_bounds caps 128).
// Codebook + c2 read via block-uniform addresses -> compiler emits s_load
// into SGPRs (broadcast via scalar pipe; v_fma v,v,s,v). No LDS in main loop.
// dist = fl( fl(A - 2*dot) + c2 ), dot = ascending-d FMA chain, strict-< argmin.
__global__ __launch_bounds__(256, 4) void vq_main(const float* __restrict__ z_e,
                                                  const float* __restrict__ cb,
                                                  const float* __restrict__ c2,
                                                  float* __restrict__ zq_out,
                                                  float* __restrict__ tok_out,
                                                  unsigned* __restrict__ used,
                                                  double* __restrict__ loss_sum) {
    const int t   = blockIdx.y;
    const int tid = threadIdx.x;
    const int b   = blockIdx.x * 256 + tid;

    // z row -> 16 float4 registers
    const float4* zr = reinterpret_cast<const float4*>(z_e + ((size_t)b * T_N + t) * D_N);
    float4 z[16];
#pragma unroll
    for (int j = 0; j < 16; ++j) z[j] = zr[j];

    // A = sum(z*z): pre-rounded products, sequential ascending-d adds.
    float A = 0.0f;
#pragma unroll
    for (int j = 0; j < 16; ++j) {
        A = __fadd_rn(A, __fmul_rn(z[j].x, z[j].x));
        A = __fadd_rn(A, __fmul_rn(z[j].y, z[j].y));
        A = __fadd_rn(A, __fmul_rn(z[j].z, z[j].z));
        A = __fadd_rn(A, __fmul_rn(z[j].w, z[j].w));
    }

    const float* cbt = cb + (size_t)t * K_N * D_N;   // block-uniform
    const float* c2t = c2 + t * K_N;                 // block-uniform

    float best = __builtin_inff();
    int tok = 0;
#pragma unroll 2
    for (int k = 0; k < K_N; ++k) {
        const float* crow = cbt + k * D_N;           // uniform -> s_load
        float a = 0.0f;
#pragma unroll
        for (int j = 0; j < 16; ++j) {
            a = __builtin_fmaf(z[j].x, crow[4 * j + 0], a);
            a = __builtin_fmaf(z[j].y, crow[4 * j + 1], a);
            a = __builtin_fmaf(z[j].z, crow[4 * j + 2], a);
            a = __builtin_fmaf(z[j].w, crow[4 * j + 3], a);
        }
        float dist = __fadd_rn(__fsub_rn(A, __fmul_rn(2.0f, a)), c2t[k]);
        if (dist < best) { best = dist; tok = k; }   // strict <: first-occurrence ties
    }

    // Epilogue: z_q_st = winning codebook row; loss in double.
    const float4* q = reinterpret_cast<const float4*>(cbt + (size_t)tok * D_N);
    float4* zq = reinterpret_cast<float4*>(zq_out + ((size_t)b * T_N + t) * D_N);
    double ld = 0.0;
#pragma unroll
    for (int j = 0; j < 16; ++j) {
        float4 qv = q[j];
        zq[j] = qv;
        float d0 = z[j].x - qv.x, d1 = z[j].y - qv.y;
        float d2 = z[j].z - qv.z, d3 = z[j].w - qv.w;
        ld += (double)d0 * d0 + (double)d1 * d1 + (double)d2 * d2 + (double)d3 * d3;
    }
    tok_out[(size_t)b * T_N + t] = (float)tok;
    used[t * K_N + tok] = 1u;

    __shared__ double red[256];
    red[tid] = ld;
    __syncthreads();
    for (int s = 128; s > 0; s >>= 1) {
        if (tid < s) red[tid] += red[tid + s];
        __syncthreads();
    }
    if (tid == 0) atomicAdd(loss_sum, red[0]);
}

__global__ __launch_bounds__(1024) void finalize_kernel(const unsigned* __restrict__ used,
                                                        const double* __restrict__ loss_sum,
                                                        float* __restrict__ out) {
    __shared__ unsigned s[1024];
    const uint4* u4 = reinterpret_cast<const uint4*>(used);
    unsigned c = 0;
#pragma unroll
    for (int i = 0; i < 8; ++i) {
        uint4 v = u4[threadIdx.x + i * 1024];
        c += v.x + v.y + v.z + v.w;
    }
    s[threadIdx.x] = c;
    __syncthreads();
    for (int st = 512; st > 0; st >>= 1) {
        if (threadIdx.x < st) s[threadIdx.x] += s[threadIdx.x + st];
        __syncthreads();
    }
    if (threadIdx.x == 0) {
        const size_t base = (size_t)B_N * T_N * D_N + (size_t)B_N * T_N;
        out[base]     = (float)(0.25 * (*loss_sum) / (double)((size_t)B_N * T_N * D_N));
        out[base + 1] = (float)s[0] / (float)(T_N * K_N);
    }
}

extern "C" void kernel_launch(void* const* d_in, const int* in_sizes, int n_in,
                              void* d_out, int out_size, void* d_ws, size_t ws_size,
                              hipStream_t stream) {
    const float* z_e = (const float*)d_in[0];
    const float* cb  = (const float*)d_in[1];
    float* out = (float*)d_out;

    float*    c2   = (float*)d_ws;
    unsigned* used = (unsigned*)((char*)d_ws + 131072);
    double*   loss = (double*)((char*)d_ws + 262144);

    hipMemsetAsync(used, 0, 131072 + 8, stream);
    c2_kernel<<<128, 256, 0, stream>>>(cb, c2);

    float* tok_out = out + (size_t)B_N * T_N * D_N;
    vq_main<<<dim3(B_N / 256, T_N), 256, 0, stream>>>(z_e, cb, c2, out, tok_out, used, loss);

    finalize_kernel<<<1, 1024, 0, stream>>>(used, loss, out);
}

// Round 5
// 429.833 us; speedup vs baseline: 1.2729x; 1.2729x over previous
//
#include <hip/hip_runtime.h>

#define B_N 4096
#define T_N 64
#define K_N 512
#define D_N 64

// ws layout:
//   [0, 131072)        : used[t*K+k] (32768 uints)
//   [131072, 131080)   : loss_sum (double)
// both zeroed by one hipMemsetAsync.

// Main kernel: block = 256 threads, fixed t, 512 consecutive b-rows,
// M=2 rows/thread with z pinned in VGPRs (asm-laundered so the allocator
// cannot rematerialize from memory). Codebook rows + c2 are block-uniform:
// codebook via scalar loads (s_load -> SGPR broadcast, v_fma v,v,s),
// c2 computed once into LDS by the prologue.
// dist = fl( fl(A - 2*dot) + c2 ), dot = ascending-d FMA chain, strict-< argmin.
__global__ __launch_bounds__(256, 2) void vq_main(const float* __restrict__ z_e,
                                                  const float* __restrict__ cb,
                                                  float* __restrict__ zq_out,
                                                  float* __restrict__ tok_out,
                                                  unsigned* __restrict__ used,
                                                  double* __restrict__ loss_sum) {
    const int t   = blockIdx.y;
    const int tid = threadIdx.x;
    const int b0  = blockIdx.x * 512 + 2 * tid;
    const int b1  = b0 + 1;

    const float* cbt = cb + (size_t)t * K_N * D_N;

    __shared__ float  c2s[K_N];
    __shared__ double red[256];

    // ---- prologue: c2 for codes 2*tid, 2*tid+1 (pre-rounded squares,
    // sequential ascending-d adds -- matches jnp.sum(c*c, axis=-1)) ----
    {
        const float4* c = reinterpret_cast<const float4*>(cbt) + (size_t)(2 * tid) * 16;
        float s0 = 0.0f, s1 = 0.0f;
#pragma unroll
        for (int j = 0; j < 16; ++j) {
            float4 v0 = c[j];
            float4 v1 = c[16 + j];
            s0 = __fadd_rn(s0, __fmul_rn(v0.x, v0.x));
            s0 = __fadd_rn(s0, __fmul_rn(v0.y, v0.y));
            s0 = __fadd_rn(s0, __fmul_rn(v0.z, v0.z));
            s0 = __fadd_rn(s0, __fmul_rn(v0.w, v0.w));
            s1 = __fadd_rn(s1, __fmul_rn(v1.x, v1.x));
            s1 = __fadd_rn(s1, __fmul_rn(v1.y, v1.y));
            s1 = __fadd_rn(s1, __fmul_rn(v1.z, v1.z));
            s1 = __fadd_rn(s1, __fmul_rn(v1.w, v1.w));
        }
        c2s[2 * tid]     = s0;
        c2s[2 * tid + 1] = s1;
    }

    // ---- z rows -> registers, laundered so they stay there ----
    float z0[D_N], z1[D_N];
    {
        const float4* zr0 = reinterpret_cast<const float4*>(z_e + ((size_t)b0 * T_N + t) * D_N);
        const float4* zr1 = reinterpret_cast<const float4*>(z_e + ((size_t)b1 * T_N + t) * D_N);
#pragma unroll
        for (int j = 0; j < 16; ++j) {
            float4 v0 = zr0[j];
            float4 v1 = zr1[j];
            z0[4*j+0] = v0.x; z0[4*j+1] = v0.y; z0[4*j+2] = v0.z; z0[4*j+3] = v0.w;
            z1[4*j+0] = v1.x; z1[4*j+1] = v1.y; z1[4*j+2] = v1.z; z1[4*j+3] = v1.w;
        }
    }
#pragma unroll
    for (int j = 0; j < D_N; ++j) {
        asm volatile("" : "+v"(z0[j]));
        asm volatile("" : "+v"(z1[j]));
    }

    // A = sum(z*z): pre-rounded products, sequential ascending-d adds.
    float A0 = 0.0f, A1 = 0.0f;
#pragma unroll
    for (int j = 0; j < D_N; ++j) A0 = __fadd_rn(A0, __fmul_rn(z0[j], z0[j]));
#pragma unroll
    for (int j = 0; j < D_N; ++j) A1 = __fadd_rn(A1, __fmul_rn(z1[j], z1[j]));

    __syncthreads();   // c2s ready

    // ---- main loop: codebook row via uniform scalar loads ----
    float best0 = __builtin_inff(), best1 = __builtin_inff();
    int tok0 = 0, tok1 = 0;
    for (int k = 0; k < K_N; ++k) {
        const float* crow = cbt + k * D_N;   // block-uniform -> s_load
        float a0 = 0.0f, a1 = 0.0f;
#pragma unroll
        for (int j = 0; j < D_N; ++j) {
            float cv = crow[j];
            a0 = __builtin_fmaf(z0[j], cv, a0);
            a1 = __builtin_fmaf(z1[j], cv, a1);
        }
        float c2k = c2s[k];
        float dist0 = __fadd_rn(__fsub_rn(A0, __fmul_rn(2.0f, a0)), c2k);
        float dist1 = __fadd_rn(__fsub_rn(A1, __fmul_rn(2.0f, a1)), c2k);
        if (dist0 < best0) { best0 = dist0; tok0 = k; }   // strict <: first-occurrence
        if (dist1 < best1) { best1 = dist1; tok1 = k; }
    }

    // ---- epilogue: z_q_st = winning codebook row; loss in double ----
    const float4* q0 = reinterpret_cast<const float4*>(cbt + (size_t)tok0 * D_N);
    const float4* q1 = reinterpret_cast<const float4*>(cbt + (size_t)tok1 * D_N);
    float4* zq0 = reinterpret_cast<float4*>(zq_out + ((size_t)b0 * T_N + t) * D_N);
    float4* zq1 = reinterpret_cast<float4*>(zq_out + ((size_t)b1 * T_N + t) * D_N);
    double ld = 0.0;
#pragma unroll
    for (int j = 0; j < 16; ++j) {
        float4 qv = q0[j];
        zq0[j] = qv;
        float d0 = z0[4*j+0] - qv.x, d1 = z0[4*j+1] - qv.y;
        float d2 = z0[4*j+2] - qv.z, d3 = z0[4*j+3] - qv.w;
        ld += (double)d0*d0 + (double)d1*d1 + (double)d2*d2 + (double)d3*d3;
    }
#pragma unroll
    for (int j = 0; j < 16; ++j) {
        float4 qv = q1[j];
        zq1[j] = qv;
        float d0 = z1[4*j+0] - qv.x, d1 = z1[4*j+1] - qv.y;
        float d2 = z1[4*j+2] - qv.z, d3 = z1[4*j+3] - qv.w;
        ld += (double)d0*d0 + (double)d1*d1 + (double)d2*d2 + (double)d3*d3;
    }
    tok_out[(size_t)b0 * T_N + t] = (float)tok0;
    tok_out[(size_t)b1 * T_N + t] = (float)tok1;
    used[t * K_N + tok0] = 1u;
    used[t * K_N + tok1] = 1u;

    red[tid] = ld;
    __syncthreads();
    for (int s = 128; s > 0; s >>= 1) {
        if (tid < s) red[tid] += red[tid + s];
        __syncthreads();
    }
    if (tid == 0) atomicAdd(loss_sum, red[0]);
}

__global__ __launch_bounds__(1024) void finalize_kernel(const unsigned* __restrict__ used,
                                                        const double* __restrict__ loss_sum,
                                                        float* __restrict__ out) {
    __shared__ unsigned s[1024];
    const uint4* u4 = reinterpret_cast<const uint4*>(used);
    unsigned c = 0;
#pragma unroll
    for (int i = 0; i < 8; ++i) {
        uint4 v = u4[threadIdx.x + i * 1024];
        c += v.x + v.y + v.z + v.w;
    }
    s[threadIdx.x] = c;
    __syncthreads();
    for (int st = 512; st > 0; st >>= 1) {
        if (threadIdx.x < st) s[threadIdx.x] += s[threadIdx.x + st];
        __syncthreads();
    }
    if (threadIdx.x == 0) {
        const size_t base = (size_t)B_N * T_N * D_N + (size_t)B_N * T_N;
        out[base]     = (float)(0.25 * (*loss_sum) / (double)((size_t)B_N * T_N * D_N));
        out[base + 1] = (float)s[0] / (float)(T_N * K_N);
    }
}

extern "C" void kernel_launch(void* const* d_in, const int* in_sizes, int n_in,
                              void* d_out, int out_size, void* d_ws, size_t ws_size,
                              hipStream_t stream) {
    const float* z_e = (const float*)d_in[0];
    const float* cb  = (const float*)d_in[1];
    float* out = (float*)d_out;

    unsigned* used = (unsigned*)d_ws;
    double*   loss = (double*)((char*)d_ws + 131072);

    hipMemsetAsync(used, 0, 131072 + 8, stream);

    float* tok_out = out + (size_t)B_N * T_N * D_N;
    vq_main<<<dim3(B_N / 512, T_N), 256, 0, stream>>>(z_e, cb, out, tok_out, used, loss);

    finalize_kernel<<<1, 1024, 0, stream>>>(used, loss, out);
}